// Round 1
// baseline (809.886 us; speedup 1.0000x reference)
//
#include <hip/hip_runtime.h>
#include <hip/hip_fp16.h>

// VQC statevector simulator, register-resident.
// One block = one batch sample. 256 threads x 64 complex amps/thread = 2^14 state.
// Layout L1: global idx i = o*256 + t  (qubits 0-7 = thread bits, 8-13 = reg bits)
// Layout L0: global idx j = t*64 + o   (qubits 0-5 = reg bits, 6-11 = lane bits, 12-13 = wave bits)
// CNOT chain (c=i,t=i+1, i=0..12) == index permutation j_k = XOR_{m<=k} i_m;
// inverse: src = (j ^ (j<<1)) & 0x3FFF  -> applied in one LDS round-trip.
// LDS holds fp16-packed state (64 KB) only during re-layout sweeps.

#define DEV static __device__ __forceinline__

constexpr int NQ  = 14;
constexpr int DIM = 1 << NQ;     // 16384
constexpr int NT  = 256;         // threads per block
constexpr int APT = DIM / NT;    // 64 amps per thread
constexpr int NL  = 4;

DEV int swz(int idx) { return idx ^ ((idx >> 6) & 31); }  // bank-conflict swizzle

__global__ __launch_bounds__(NT, 2)
void vqc_kernel(const float* __restrict__ inputs,
                const float* __restrict__ weights,
                float* __restrict__ out)
{
    extern __shared__ __half2 lds[];   // DIM entries = 64 KB
    const int t = threadIdx.x;
    const int b = blockIdx.x;

    float ar[APT], ai[APT];

    // ---- Encoding: RY(x_q) on |0..0> is a product state; build directly in L1 ----
    float cq[NQ], sq[NQ];
#pragma unroll
    for (int q = 0; q < NQ; ++q) {
        float x = 0.5f * inputs[b * NQ + q];
        __sincosf(x, &sq[q], &cq[q]);
    }
    float Ft = 1.0f;
#pragma unroll
    for (int q = 0; q < 8; ++q)
        Ft *= ((t >> q) & 1) ? sq[q] : cq[q];
#pragma unroll
    for (int o = 0; o < APT; ++o) {
        float v = Ft;
#pragma unroll
        for (int m = 0; m < 6; ++m)
            v *= ((o >> m) & 1) ? sq[8 + m] : cq[8 + m];
        ar[o] = v;
        ai[o] = 0.0f;
    }

    // ---- Variational layers ----
#pragma unroll 1
    for (int layer = 0; layer < NL; ++layer) {
        const float* wl = weights + layer * NQ;

        // Sweep A: state (L1) -> LDS -> read with CNOT-chain permutation into L0
        __syncthreads();
#pragma unroll
        for (int o = 0; o < APT; ++o)
            lds[swz(o * NT + t)] = __floats2half2_rn(ar[o], ai[o]);
        __syncthreads();
#pragma unroll
        for (int o = 0; o < APT; ++o) {
            int j   = t * APT + o;
            int src = (j ^ (j << 1)) & (DIM - 1);
            float2 f = __half22float2(lds[swz(src)]);
            ar[o] = f.x; ai[o] = f.y;
        }

        // RX on qubits 0..5 (register-local bits of o in L0)
#pragma unroll
        for (int q = 0; q < 6; ++q) {
            float s, c;
            __sincosf(0.5f * wl[q], &s, &c);
#pragma unroll
            for (int o = 0; o < APT; ++o) {
                if (o & (1 << q)) continue;
                int o1 = o | (1 << q);
                float a0r = ar[o],  a0i = ai[o];
                float a1r = ar[o1], a1i = ai[o1];
                ar[o]  = c * a0r + s * a1i;
                ai[o]  = c * a0i - s * a1r;
                ar[o1] = c * a1r + s * a0i;
                ai[o1] = c * a1i - s * a0r;
            }
        }

        // RX on qubits 6,7 (lane bits 0,1 in L0) via shuffles.
        // RX matrix is symmetric: mine' = c*mine - i*s*partner for both sides.
#pragma unroll
        for (int q = 6; q < 8; ++q) {
            float s, c;
            __sincosf(0.5f * wl[q], &s, &c);
            const int mask = 1 << (q - 6);
#pragma unroll
            for (int o = 0; o < APT; ++o) {
                float pr = __shfl_xor(ar[o], mask, 64);
                float pi = __shfl_xor(ai[o], mask, 64);
                ar[o] = c * ar[o] + s * pi;
                ai[o] = c * ai[o] - s * pr;
            }
        }

        // Sweep B: transpose L0 -> L1
        __syncthreads();
#pragma unroll
        for (int o = 0; o < APT; ++o)
            lds[swz(t * APT + o)] = __floats2half2_rn(ar[o], ai[o]);
        __syncthreads();
#pragma unroll
        for (int o = 0; o < APT; ++o) {
            float2 f = __half22float2(lds[swz(o * NT + t)]);
            ar[o] = f.x; ai[o] = f.y;
        }

        // RX on qubits 8..13 (register-local bits of o in L1)
#pragma unroll
        for (int q = 8; q < NQ; ++q) {
            float s, c;
            __sincosf(0.5f * wl[q], &s, &c);
            const int bit = q - 8;
#pragma unroll
            for (int o = 0; o < APT; ++o) {
                if (o & (1 << bit)) continue;
                int o1 = o | (1 << bit);
                float a0r = ar[o],  a0i = ai[o];
                float a1r = ar[o1], a1i = ai[o1];
                ar[o]  = c * a0r + s * a1i;
                ai[o]  = c * a0i - s * a1r;
                ar[o1] = c * a1r + s * a0i;
                ai[o1] = c * a1i - s * a0r;
            }
        }
    }

    // ---- Z expectations (state in L1: qubits 0-7 = t bits, 8-13 = o bits) ----
    float S[7] = {0, 0, 0, 0, 0, 0, 0};  // S[0]=total prob, S[1+m] = signed sum for qubit 8+m
#pragma unroll
    for (int o = 0; o < APT; ++o) {
        float p = ar[o] * ar[o] + ai[o] * ai[o];
        S[0] += p;
#pragma unroll
        for (int m = 0; m < 6; ++m)
            S[1 + m] += ((o >> m) & 1) ? -p : p;
    }

    __syncthreads();                                   // protect final sweep reads
    float* red = reinterpret_cast<float*>(lds);
#pragma unroll
    for (int m = 0; m < 7; ++m)
        red[t * 7 + m] = S[m];
    __syncthreads();

    if (t < NQ) {
        float acc = 0.0f;
        if (t < 8) {
            for (int tt = 0; tt < NT; ++tt) {
                float v = red[tt * 7];
                acc += ((tt >> t) & 1) ? -v : v;
            }
        } else {
            for (int tt = 0; tt < NT; ++tt)
                acc += red[tt * 7 + (t - 7)];
        }
        out[b * NQ + t] = acc;
    }
}

extern "C" void kernel_launch(void* const* d_in, const int* in_sizes, int n_in,
                              void* d_out, int out_size, void* d_ws, size_t ws_size,
                              hipStream_t stream)
{
    const float* inputs  = (const float*)d_in[0];
    const float* weights = (const float*)d_in[1];
    float* out = (float*)d_out;

    const int Bn = in_sizes[0] / NQ;   // 1024
    vqc_kernel<<<dim3(Bn), dim3(NT), DIM * sizeof(__half2), stream>>>(inputs, weights, out);
}

// Round 2
// 230.437 us; speedup vs baseline: 3.5146x; 3.5146x over previous
//
#include <hip/hip_runtime.h>
#include <hip/hip_fp16.h>

// VQC statevector simulator, register-resident, v2 (fix R1 register spill).
// One block = one batch sample. 1024 threads x 16 complex amps/thread = 2^14.
// Layout L1: global idx i = o*1024 + t  (qubits 0-9 = thread bits, 10-13 = reg bits)
// Layout L0: global idx j = t*16 + o    (qubits 0-3 = reg bits, 4-9 = lane bits, 10-13 = wave bits)
// CNOT chain (c=i,t=i+1, i=0..12) == prefix-XOR permutation;
// inverse: src = (j ^ (j<<1)) & 0x3FFF -> applied in one LDS round-trip.
// LDS holds fp16-packed state (64 KB) only during the two re-layout sweeps per layer.

constexpr int NQ  = 14;
constexpr int DIM = 1 << NQ;     // 16384
constexpr int NT  = 1024;        // threads per block (16 waves)
constexpr int APT = DIM / NT;    // 16 amps per thread
constexpr int NL  = 4;

static __device__ __forceinline__ int swz(int idx) { return idx ^ ((idx >> 6) & 31); }

__global__ __launch_bounds__(NT, 4)
void vqc_kernel(const float* __restrict__ inputs,
                const float* __restrict__ weights,
                float* __restrict__ out)
{
    extern __shared__ __half2 lds[];   // DIM entries = 64 KB
    const int t    = threadIdx.x;
    const int b    = blockIdx.x;
    const int lane = t & 63;
    const int wv   = t >> 6;

    float ar[APT], ai[APT];

    // ---- Encoding: RY(x_q) on |0..0> is a product state; build directly in L1 ----
    float Ft = 1.0f;
#pragma unroll
    for (int q = 0; q < 10; ++q) {
        float s, c;
        __sincosf(0.5f * inputs[b * NQ + q], &s, &c);
        Ft *= ((t >> q) & 1) ? s : c;
    }
    float co[4], so[4];
#pragma unroll
    for (int m = 0; m < 4; ++m)
        __sincosf(0.5f * inputs[b * NQ + 10 + m], &so[m], &co[m]);
#pragma unroll
    for (int o = 0; o < APT; ++o) {
        float v = Ft;
#pragma unroll
        for (int m = 0; m < 4; ++m)
            v *= ((o >> m) & 1) ? so[m] : co[m];
        ar[o] = v;
        ai[o] = 0.0f;
    }

    // ---- Variational layers ----
#pragma unroll 1
    for (int layer = 0; layer < NL; ++layer) {
        const float* wl = weights + layer * NQ;

        // Sweep A: state (L1) -> LDS -> read with CNOT-chain permutation into L0
        __syncthreads();
#pragma unroll
        for (int o = 0; o < APT; ++o)
            lds[swz(o * NT + t)] = __floats2half2_rn(ar[o], ai[o]);
        __syncthreads();
#pragma unroll
        for (int o = 0; o < APT; ++o) {
            int j   = t * APT + o;
            int src = (j ^ (j << 1)) & (DIM - 1);
            float2 f = __half22float2(lds[swz(src)]);
            ar[o] = f.x; ai[o] = f.y;
        }

        // RX on qubits 0..3 (register-local bits of o in L0)
#pragma unroll
        for (int q = 0; q < 4; ++q) {
            float s, c;
            __sincosf(0.5f * wl[q], &s, &c);
#pragma unroll
            for (int o = 0; o < APT; ++o) {
                if (o & (1 << q)) continue;
                int o1 = o | (1 << q);
                float a0r = ar[o],  a0i = ai[o];
                float a1r = ar[o1], a1i = ai[o1];
                ar[o]  = c * a0r + s * a1i;
                ai[o]  = c * a0i - s * a1r;
                ar[o1] = c * a1r + s * a0i;
                ai[o1] = c * a1i - s * a0r;
            }
        }

        // RX on qubits 4..9 (lane bits 0..5 in L0) via shuffles.
        // RX is symmetric: mine' = c*mine - i*s*partner for both sides.
#pragma unroll
        for (int q = 4; q < 10; ++q) {
            float s, c;
            __sincosf(0.5f * wl[q], &s, &c);
            const int mask = 1 << (q - 4);
#pragma unroll
            for (int o = 0; o < APT; ++o) {
                float pr = __shfl_xor(ar[o], mask, 64);
                float pi = __shfl_xor(ai[o], mask, 64);
                ar[o] = c * ar[o] + s * pi;
                ai[o] = c * ai[o] - s * pr;
            }
        }

        // Sweep B: transpose L0 -> L1
        __syncthreads();
#pragma unroll
        for (int o = 0; o < APT; ++o)
            lds[swz(t * APT + o)] = __floats2half2_rn(ar[o], ai[o]);
        __syncthreads();
#pragma unroll
        for (int o = 0; o < APT; ++o) {
            float2 f = __half22float2(lds[swz(o * NT + t)]);
            ar[o] = f.x; ai[o] = f.y;
        }

        // RX on qubits 10..13 (register-local bits of o in L1)
#pragma unroll
        for (int q = 10; q < NQ; ++q) {
            float s, c;
            __sincosf(0.5f * wl[q], &s, &c);
            const int bit = q - 10;
#pragma unroll
            for (int o = 0; o < APT; ++o) {
                if (o & (1 << bit)) continue;
                int o1 = o | (1 << bit);
                float a0r = ar[o],  a0i = ai[o];
                float a1r = ar[o1], a1i = ai[o1];
                ar[o]  = c * a0r + s * a1i;
                ai[o]  = c * a0i - s * a1r;
                ar[o1] = c * a1r + s * a0i;
                ai[o1] = c * a1i - s * a0r;
            }
        }
    }

    // ---- Z expectations. State in L1: qubits 0-5 = lane bits, 6-9 = wave bits,
    //      10-13 = reg bits of o. ----
    float ptot = 0.0f, Sq[4] = {0, 0, 0, 0};
#pragma unroll
    for (int o = 0; o < APT; ++o) {
        float p = ar[o] * ar[o] + ai[o] * ai[o];
        ptot += p;
#pragma unroll
        for (int m = 0; m < 4; ++m)
            Sq[m] += ((o >> m) & 1) ? -p : p;
    }

    // Wave-level butterfly reduce: plain sums for ptot and Sq[0..3];
    // signed sums (Walsh) for lane-bit qubits 0..5.
    float accL[6];
#pragma unroll
    for (int k = 0; k < 6; ++k) accL[k] = ptot;
#pragma unroll
    for (int k = 0; k < 6; ++k) {
        const int m = 1 << k;
#pragma unroll
        for (int j = 0; j < 6; ++j) {
            float pr = __shfl_xor(accL[j], m, 64);
            if (j == k)
                accL[j] = ((lane >> k) & 1) ? (pr - accL[j]) : (accL[j] - pr);
            else
                accL[j] += pr;
        }
        ptot += __shfl_xor(ptot, m, 64);
#pragma unroll
        for (int j = 0; j < 4; ++j) Sq[j] += __shfl_xor(Sq[j], m, 64);
    }

    // Per-wave results -> LDS, tiny cross-wave combine.
    float* red = reinterpret_cast<float*>(lds);
    __syncthreads();                      // LDS no longer needed for state
    if (lane == 0) {
        red[wv * 12 + 0] = ptot;          // wave total prob
#pragma unroll
        for (int k = 0; k < 6; ++k) red[wv * 12 + 1 + k] = accL[k];   // qubits 0..5
#pragma unroll
        for (int m = 0; m < 4; ++m) red[wv * 12 + 7 + m] = Sq[m];     // qubits 10..13
    }
    __syncthreads();

    if (t < NQ) {
        float acc = 0.0f;
        if (t < 6) {
            for (int w = 0; w < 16; ++w) acc += red[w * 12 + 1 + t];
        } else if (t < 10) {
            const int bit = t - 6;
            for (int w = 0; w < 16; ++w) {
                float v = red[w * 12];
                acc += ((w >> bit) & 1) ? -v : v;
            }
        } else {
            for (int w = 0; w < 16; ++w) acc += red[w * 12 + 7 + (t - 10)];
        }
        out[b * NQ + t] = acc;
    }
}

extern "C" void kernel_launch(void* const* d_in, const int* in_sizes, int n_in,
                              void* d_out, int out_size, void* d_ws, size_t ws_size,
                              hipStream_t stream)
{
    const float* inputs  = (const float*)d_in[0];
    const float* weights = (const float*)d_in[1];
    float* out = (float*)d_out;

    const int Bn = in_sizes[0] / NQ;   // 1024
    vqc_kernel<<<dim3(Bn), dim3(NT), DIM * sizeof(__half2), stream>>>(inputs, weights, out);
}